// Round 10
// baseline (297.960 us; speedup 1.0000x reference)
//
#include <hip/hip_runtime.h>

// out = x @ M^65 @ w_out^T,  M = 0.9 I + 0.1 W  (early-stop provably never fires:
// |eig(M)| in [0.81,0.99] => norm(h)/B stays ~4 orders above 1e-6 for all 65 steps).
// M^65 via repeated squaring, SPLIT-bf16 MFMA (hi+lo, 3 products, fp32 accum).
// ONE persistent 256-block kernel runs the whole chain (build -> 6 squarings ->
// Q-fold -> P-fold) with hand-rolled grid barriers. 128 KB LDS/block forces
// 1 block/CU => all 256 blocks co-resident => barrier is deadlock-free.
// Then one 16384x512x256 bf16-MFMA GEMM (gld_lds staging, counted vmcnt).

typedef __attribute__((ext_vector_type(4))) float f32x4;
typedef __attribute__((ext_vector_type(2))) float f32x2;
typedef __attribute__((ext_vector_type(8))) short bf16x8;
typedef __attribute__((ext_vector_type(4))) unsigned short u16x4;

typedef __attribute__((address_space(1))) const unsigned int guint;
typedef __attribute__((address_space(3))) unsigned int luint;

__device__ __forceinline__ void gld_lds16(const void* g, void* l) {
    __builtin_amdgcn_global_load_lds((guint*)g, (luint*)l, 16, 0, 0);
}

__device__ __forceinline__ unsigned short f2bf(float f) {
    unsigned int u = __float_as_uint(f);
    return (unsigned short)((u + 0x7fffu + ((u >> 16) & 1u)) >> 16);  // RNE
}
__device__ __forceinline__ float bf2f(unsigned short h) {
    return __uint_as_float(((unsigned int)h) << 16);
}
__device__ __forceinline__ void split2(float v, unsigned short& h, unsigned short& l) {
    h = f2bf(v);
    l = f2bf(v - bf2f(h));
}

// grid barrier: release fence + device-scope atomic count + acquire fence.
__device__ __forceinline__ void gbar(int* cnt, int idx) {
    __syncthreads();
    if (threadIdx.x == 0) {
        __threadfence();                         // release: drain + wb L2
        atomicAdd(&cnt[idx], 1);
        while (atomicAdd(&cnt[idx], 0) < 256) __builtin_amdgcn_s_sleep(2);
        __threadfence();                         // acquire: inv L1/L2
    }
    __syncthreads();
}

// One 32x32 output tile of C = A @ B (K=512), whole-K staged in 128 KB LDS.
// A row-major hi/lo; B given as B^T rows [n][k] hi/lo. 4 waves = 2x2 frag grid.
// OUTMODE 0: C hi/lo + C^T hi/lo; 1: C^T hi/lo; 2: C^T single bf16.
template<int OUTMODE>
__device__ __forceinline__ void mm_tile(
        const unsigned short* __restrict__ Agh, const unsigned short* __restrict__ Agl,
        const unsigned short* __restrict__ BTh, const unsigned short* __restrict__ BTl,
        unsigned short* __restrict__ Ch, unsigned short* __restrict__ Cl,
        unsigned short* __restrict__ CTh, unsigned short* __restrict__ CTl,
        int row0, int col0, char* lds) {
    const int tid = threadIdx.x, lane = tid & 63, w = tid >> 6;
    const int wr = w >> 1, wc = w & 1, l16 = lane & 15, ks = lane >> 4;
    // stage 4 arrays x [32 rows][1024 B]; dest linear, source col pre-swizzled
    const int t6 = tid >> 6, c64 = (tid & 63) << 4;
    #pragma unroll
    for (int i = 0; i < 8; ++i) {
        const int r = (i << 2) + t6;
        const int gcol = (c64 ^ ((r & 7) << 4)) >> 1;       // u16 units
        char* d = lds + (i << 12) + (tid << 4);
        gld_lds16(Agh + (row0 + r) * 512 + gcol, d);
        gld_lds16(Agl + (row0 + r) * 512 + gcol, d + 32768);
        gld_lds16(BTh + (col0 + r) * 512 + gcol, d + 65536);
        gld_lds16(BTl + (col0 + r) * 512 + gcol, d + 98304);
    }
    asm volatile("s_waitcnt vmcnt(0)" ::: "memory");
    __builtin_amdgcn_sched_barrier(0);
    __builtin_amdgcn_s_barrier();

    f32x4 acc0 = {}, acc1 = {}, acc2 = {};
    const int sw = (l16 & 7) << 4;
    const int ra = (wr * 16 + l16) << 10;
    const int rb = (wc * 16 + l16) << 10;
    #pragma unroll
    for (int s = 0; s < 16; ++s) {
        const int qo = ((s << 6) + (ks << 4)) ^ sw;
        bf16x8 ah = *(const bf16x8*)(lds + ra + qo);
        bf16x8 al = *(const bf16x8*)(lds + 32768 + ra + qo);
        bf16x8 bh = *(const bf16x8*)(lds + 65536 + rb + qo);
        bf16x8 bl = *(const bf16x8*)(lds + 98304 + rb + qo);
        acc0 = __builtin_amdgcn_mfma_f32_16x16x32_bf16(ah, bh, acc0, 0, 0, 0);
        acc1 = __builtin_amdgcn_mfma_f32_16x16x32_bf16(ah, bl, acc1, 0, 0, 0);
        acc2 = __builtin_amdgcn_mfma_f32_16x16x32_bf16(al, bh, acc2, 0, 0, 0);
    }

    const int orow = row0 + wr * 16 + (ks << 2);  // C/D: col=lane&15, row=(lane>>4)*4+j
    const int ocol = col0 + wc * 16 + l16;
    float cv[4];
    #pragma unroll
    for (int j = 0; j < 4; ++j) cv[j] = acc0[j] + acc1[j] + acc2[j];
    if (OUTMODE == 2) {
        u16x4 t4;
        #pragma unroll
        for (int j = 0; j < 4; ++j) t4[j] = f2bf(cv[j]);
        *(u16x4*)&CTh[ocol * 512 + orow] = t4;
    } else {
        u16x4 th4, tl4;
        #pragma unroll
        for (int j = 0; j < 4; ++j) {
            unsigned short hh, ll; split2(cv[j], hh, ll);
            th4[j] = hh; tl4[j] = ll;
            if (OUTMODE == 0) {
                Ch[(orow + j) * 512 + ocol] = hh;
                Cl[(orow + j) * 512 + ocol] = ll;
            }
        }
        *(u16x4*)&CTh[ocol * 512 + orow] = th4;
        *(u16x4*)&CTl[ocol * 512 + orow] = tl4;
    }
}

__global__ __launch_bounds__(256) void reservoir_chain(
        const float* __restrict__ W, const float* __restrict__ wo,
        unsigned short* __restrict__ u, int* __restrict__ cnt) {
    __shared__ __align__(128) char lds[131072];
    const int tid = threadIdx.x, bid = blockIdx.x;

    const size_t SZ = 512 * 512;
    unsigned short *SMh = u,           *SMl = u + SZ,     *SMTh = u + 2 * SZ, *SMTl = u + 3 * SZ;
    unsigned short *S0h = u + 4 * SZ,  *S0l = u + 5 * SZ, *S0Th = u + 6 * SZ, *S0Tl = u + 7 * SZ;
    unsigned short *S1h = u + 8 * SZ,  *S1l = u + 9 * SZ, *S1Th = u + 10 * SZ, *S1Tl = u + 11 * SZ;
    unsigned short *WOh = u + 12 * SZ, *WOl = WOh + 131072;
    unsigned short *QTh = u + 13 * SZ, *QTl = QTh + 131072;
    unsigned short *Ptb = u + 14 * SZ;

    // ---- stage 0: M = 0.9I + 0.1W split hi/lo (+transpose), w_out split ----
    {
        unsigned short (*Lh)[40] = (unsigned short (*)[40])lds;
        unsigned short (*Ll)[40] = (unsigned short (*)[40])(lds + 2560);
        const int row0 = (bid >> 4) << 5, col0 = (bid & 15) << 5;
        const int r = tid >> 3, c4 = (tid & 7) << 2;
        f32x4 v = *(const f32x4*)&W[(row0 + r) * 512 + col0 + c4];
        u16x4 h4, l4;
        #pragma unroll
        for (int j = 0; j < 4; ++j) {
            float val = 0.1f * v[j];
            if (row0 + r == col0 + c4 + j) val += 0.9f;
            unsigned short hh, ll; split2(val, hh, ll);
            h4[j] = hh; l4[j] = ll;
        }
        *(u16x4*)&SMh[(row0 + r) * 512 + col0 + c4] = h4;
        *(u16x4*)&SMl[(row0 + r) * 512 + col0 + c4] = l4;
        *(u16x4*)&Lh[r][c4] = h4;
        *(u16x4*)&Ll[r][c4] = l4;
        // w_out split: this block handles 512 consecutive floats
        const int i2 = (bid << 9) + (tid << 1);
        f32x2 wv = *(const f32x2*)&wo[i2];
        unsigned short wh, wl;
        split2(wv.x, wh, wl); WOh[i2] = wh;     WOl[i2] = wl;
        split2(wv.y, wh, wl); WOh[i2 + 1] = wh; WOl[i2 + 1] = wl;
        __syncthreads();
        const int c = tid >> 3, rr = (tid & 7) << 2;
        u16x4 th, tl;
        #pragma unroll
        for (int j = 0; j < 4; ++j) { th[j] = Lh[rr + j][c]; tl[j] = Ll[rr + j][c]; }
        *(u16x4*)&SMTh[(col0 + c) * 512 + row0 + rr] = th;
        *(u16x4*)&SMTl[(col0 + c) * 512 + row0 + rr] = tl;
    }
    gbar(cnt, 0);

    const int sr0 = (bid >> 4) << 5, sc0 = (bid & 15) << 5;   // squaring tile
    mm_tile<0>(SMh, SMl, SMTh, SMTl, S0h, S0l, S0Th, S0Tl, sr0, sc0, lds); gbar(cnt, 1); // M^2
    mm_tile<0>(S0h, S0l, S0Th, S0Tl, S1h, S1l, S1Th, S1Tl, sr0, sc0, lds); gbar(cnt, 2); // M^4
    mm_tile<0>(S1h, S1l, S1Th, S1Tl, S0h, S0l, S0Th, S0Tl, sr0, sc0, lds); gbar(cnt, 3); // M^8
    mm_tile<0>(S0h, S0l, S0Th, S0Tl, S1h, S1l, S1Th, S1Tl, sr0, sc0, lds); gbar(cnt, 4); // M^16
    mm_tile<0>(S1h, S1l, S1Th, S1Tl, S0h, S0l, S0Th, S0Tl, sr0, sc0, lds); gbar(cnt, 5); // M^32
    mm_tile<0>(S0h, S0l, S0Th, S0Tl, S1h, S1l, S1Th, S1Tl, sr0, sc0, lds); gbar(cnt, 6); // M^64 -> S1

    if (bid < 128) {   // Q^T = (M @ w_out^T)^T  (reads SM, intact)
        const int qr0 = (bid >> 3) << 5, qc0 = (bid & 7) << 5;
        mm_tile<1>(SMh, SMl, WOh, WOl, nullptr, nullptr, QTh, QTl, qr0, qc0, lds);
    }
    gbar(cnt, 7);
    if (bid < 128) {   // Pt = (M^64 @ Q)^T single bf16
        const int qr0 = (bid >> 3) << 5, qc0 = (bid & 7) << 5;
        mm_tile<2>(S1h, S1l, QTh, QTl, nullptr, nullptr, Ptb, nullptr, qr0, qc0, lds);
    }
}

// ---- out[16384 x 256] = X @ P.  Pt bf16 [256][512] = P^T (L2-resident). ----
// BM=32, BN=128 (4 waves x 32 cols), BK=64, grid (2,512) = 1024 blocks, 4/CU.
// X staged fp32 via gld_lds (pre-swizzled source); B-frags direct from L2,
// lookahead-1; vmcnt(6)-counted, raw barriers; fp32->bf16 at frag read.
__global__ __launch_bounds__(256, 4) void gemm_final(const float* __restrict__ X,
        const unsigned short* __restrict__ Pt, float* __restrict__ out) {
    __shared__ float XS[2][32][64];               // 8 KB per buffer, swizzled layout
    const int tid = threadIdx.x, lane = tid & 63, w = tid >> 6;
    const int l16 = lane & 15, ks = lane >> 4;
    const int row0 = blockIdx.y << 5, col0 = blockIdx.x << 7;

    const int srow = tid >> 4;
    const int scs  = (((tid & 15) << 4) ^ ((srow & 7) << 4)) >> 2;   // float offset
    const float* xp0 = X + (row0 + srow) * 512 + scs;
    const float* xp1 = X + (row0 + 16 + srow) * 512 + scs;
    const unsigned short* bp = Pt + (col0 + w * 32 + l16) * 512 + ks * 8;

    f32x4 acc[2][2] = {};
    bf16x8 Breg[2][4];

    #define FG_STAGE(buf, t) {                                       \
        const int k_ = (t) << 6;                                     \
        gld_lds16(xp0 + k_, (char*)XS[buf] + tid * 16);              \
        gld_lds16(xp1 + k_, (char*)XS[buf] + 4096 + tid * 16);       \
    }
    #define FG_LOADB(set, t) {                                       \
        const int k_ = (t) << 6;                                     \
        _Pragma("unroll")                                            \
        for (int n = 0; n < 2; ++n)                                  \
            _Pragma("unroll")                                        \
            for (int s = 0; s < 2; ++s)                              \
                Breg[set][n * 2 + s] =                               \
                    *(const bf16x8*)&bp[n * 8192 + k_ + s * 32];     \
    }

    FG_STAGE(0, 0);
    FG_LOADB(0, 0);
    #pragma unroll
    for (int t = 0; t < 8; ++t) {
        const int buf = t & 1;
        if (t < 7) { FG_STAGE(buf ^ 1, t + 1); FG_LOADB(buf ^ 1, t + 1); }
        if (t < 7) asm volatile("s_waitcnt vmcnt(6)" ::: "memory");
        else       asm volatile("s_waitcnt vmcnt(0)" ::: "memory");
        __builtin_amdgcn_sched_barrier(0);
        __builtin_amdgcn_s_barrier();

        const int sw = (l16 & 7) << 4;
        #pragma unroll
        for (int m = 0; m < 2; ++m) {
            bf16x8 af[2];
            #pragma unroll
            for (int s = 0; s < 2; ++s) {
                const int q = (m * 16 + l16) * 256 + s * 128 + ks * 32;
                f32x4 v0 = *(const f32x4*)((const char*)XS[buf] + (q ^ sw));
                f32x4 v1 = *(const f32x4*)((const char*)XS[buf] + ((q + 16) ^ sw));
                #pragma unroll
                for (int j = 0; j < 4; ++j) {
                    af[s][j]     = (short)f2bf(v0[j]);
                    af[s][4 + j] = (short)f2bf(v1[j]);
                }
            }
            #pragma unroll
            for (int n = 0; n < 2; ++n) {
                acc[m][n] = __builtin_amdgcn_mfma_f32_16x16x32_bf16(af[0], Breg[buf][n * 2 + 0], acc[m][n], 0, 0, 0);
                acc[m][n] = __builtin_amdgcn_mfma_f32_16x16x32_bf16(af[1], Breg[buf][n * 2 + 1], acc[m][n], 0, 0, 0);
            }
        }
        __builtin_amdgcn_s_barrier();
    }
    #undef FG_STAGE
    #undef FG_LOADB

    #pragma unroll
    for (int m = 0; m < 2; ++m)
        #pragma unroll
        for (int n = 0; n < 2; ++n)
            #pragma unroll
            for (int j = 0; j < 4; ++j)
                out[(row0 + m * 16 + ks * 4 + j) * 256 + col0 + w * 32 + n * 16 + l16] = acc[m][n][j];
}

extern "C" void kernel_launch(void* const* d_in, const int* in_sizes, int n_in,
                              void* d_out, int out_size, void* d_ws, size_t ws_size,
                              hipStream_t stream) {
    const float* x     = (const float*)d_in[0];   // 16384 x 512
    const float* W     = (const float*)d_in[1];   // 512 x 512
    const float* w_out = (const float*)d_in[2];   // 256 x 512
    float* out = (float*)d_out;                   // 16384 x 256
    unsigned short* u = (unsigned short*)d_ws;

    const size_t SZ = 512 * 512;
    unsigned short* Ptb = u + 14 * SZ;
    int* cnt = (int*)(u + 15 * SZ);

    hipMemsetAsync(cnt, 0, 128, stream);          // zero grid-barrier counters
    reservoir_chain<<<256, 256, 0, stream>>>(W, w_out, u, cnt);
    gemm_final<<<dim3(2, 512), 256, 0, stream>>>(x, Ptb, out);
}

// Round 11
// 135.961 us; speedup vs baseline: 2.1915x; 2.1915x over previous
//
#include <hip/hip_runtime.h>

// out = x @ M^65 @ w_out^T,  M = 0.9 I + 0.1 W  (early-stop provably never fires:
// |eig(M)| in [0.81,0.99] => norm(h)/B stays ~4 orders above 1e-6 for all 65 steps).
// M^65 via repeated squaring, SPLIT-bf16 MFMA (hi+lo, 3 products, fp32 accum).
// Multi-dispatch chain (implicit inter-kernel coherence -- round-10 showed explicit
// grid-barrier fences cost 31.8MB of L2-invalidation refetch). Each chain GEMM
// stages WHOLE K=512 in 128 KB LDS: one vmcnt(0) + one barrier per kernel.
// Q-fold merged into the M^2 dispatch (independent); wsplit merged into build.
// Final 16384x512x256 GEMM: round-5-proven gld_lds + vmcnt(10) pipeline.

typedef __attribute__((ext_vector_type(4))) float f32x4;
typedef __attribute__((ext_vector_type(2))) float f32x2;
typedef __attribute__((ext_vector_type(8))) short bf16x8;
typedef __attribute__((ext_vector_type(4))) unsigned short u16x4;

typedef __attribute__((address_space(1))) const unsigned int guint;
typedef __attribute__((address_space(3))) unsigned int luint;

__device__ __forceinline__ void gld_lds16(const void* g, void* l) {
    __builtin_amdgcn_global_load_lds((guint*)g, (luint*)l, 16, 0, 0);
}

__device__ __forceinline__ unsigned short f2bf(float f) {
    unsigned int u = __float_as_uint(f);
    return (unsigned short)((u + 0x7fffu + ((u >> 16) & 1u)) >> 16);  // RNE
}
__device__ __forceinline__ float bf2f(unsigned short h) {
    return __uint_as_float(((unsigned int)h) << 16);
}
__device__ __forceinline__ void split2(float v, unsigned short& h, unsigned short& l) {
    h = f2bf(v);
    l = f2bf(v - bf2f(h));
}

// ---- build: M = 0.9I + 0.1W split hi/lo (+transpose) AND w_out split ----
__global__ __launch_bounds__(256) void build_M(const float* __restrict__ W,
        const float* __restrict__ wo,
        unsigned short* __restrict__ Mh, unsigned short* __restrict__ Ml,
        unsigned short* __restrict__ MTh, unsigned short* __restrict__ MTl,
        unsigned short* __restrict__ WOh, unsigned short* __restrict__ WOl) {
    __shared__ unsigned short Lh[32][40], Ll[32][40];
    const int tid = threadIdx.x, bid = blockIdx.x;
    const int row0 = (bid >> 4) << 5, col0 = (bid & 15) << 5;
    const int r = tid >> 3, c4 = (tid & 7) << 2;
    f32x4 v = *(const f32x4*)&W[(row0 + r) * 512 + col0 + c4];
    u16x4 h4, l4;
    #pragma unroll
    for (int j = 0; j < 4; ++j) {
        float val = 0.1f * v[j];
        if (row0 + r == col0 + c4 + j) val += 0.9f;
        unsigned short hh, ll; split2(val, hh, ll);
        h4[j] = hh; l4[j] = ll;
    }
    *(u16x4*)&Mh[(row0 + r) * 512 + col0 + c4] = h4;
    *(u16x4*)&Ml[(row0 + r) * 512 + col0 + c4] = l4;
    *(u16x4*)&Lh[r][c4] = h4;
    *(u16x4*)&Ll[r][c4] = l4;
    // w_out split: 512 consecutive floats per block
    const int i2 = (bid << 9) + (tid << 1);
    f32x2 wv = *(const f32x2*)&wo[i2];
    unsigned short wh, wl;
    split2(wv.x, wh, wl); WOh[i2] = wh;     WOl[i2] = wl;
    split2(wv.y, wh, wl); WOh[i2 + 1] = wh; WOl[i2 + 1] = wl;
    __syncthreads();
    const int c = tid >> 3, rr = (tid & 7) << 2;
    u16x4 th, tl;
    #pragma unroll
    for (int j = 0; j < 4; ++j) { th[j] = Lh[rr + j][c]; tl[j] = Ll[rr + j][c]; }
    *(u16x4*)&MTh[(col0 + c) * 512 + row0 + rr] = th;
    *(u16x4*)&MTl[(col0 + c) * 512 + row0 + rr] = tl;
}

// One 32x32 output tile of C = A @ B (K=512), whole-K staged in 128 KB LDS.
// A row-major hi/lo; B as B^T rows [n][k] hi/lo. 4 waves = 2x2 of 16x16 frags.
// Exactly one vmcnt(0) + one s_barrier. (Arithmetic HW-verified in round 10.)
// OUTMODE 0: C hi/lo + C^T hi/lo; 1: C^T hi/lo; 2: C^T single bf16.
template<int OUTMODE>
__device__ __forceinline__ void mm_tile(
        const unsigned short* __restrict__ Agh, const unsigned short* __restrict__ Agl,
        const unsigned short* __restrict__ BTh, const unsigned short* __restrict__ BTl,
        unsigned short* __restrict__ Ch, unsigned short* __restrict__ Cl,
        unsigned short* __restrict__ CTh, unsigned short* __restrict__ CTl,
        int row0, int col0, char* lds) {
    const int tid = threadIdx.x, lane = tid & 63, w = tid >> 6;
    const int wr = w >> 1, wc = w & 1, l16 = lane & 15, ks = lane >> 4;
    const int t6 = tid >> 6, c64 = (tid & 63) << 4;
    #pragma unroll
    for (int i = 0; i < 8; ++i) {
        const int r = (i << 2) + t6;
        const int gcol = (c64 ^ ((r & 7) << 4)) >> 1;       // u16 units, pre-swizzled
        char* d = lds + (i << 12) + (tid << 4);
        gld_lds16(Agh + (row0 + r) * 512 + gcol, d);
        gld_lds16(Agl + (row0 + r) * 512 + gcol, d + 32768);
        gld_lds16(BTh + (col0 + r) * 512 + gcol, d + 65536);
        gld_lds16(BTl + (col0 + r) * 512 + gcol, d + 98304);
    }
    asm volatile("s_waitcnt vmcnt(0)" ::: "memory");
    __builtin_amdgcn_sched_barrier(0);
    __builtin_amdgcn_s_barrier();

    f32x4 acc0 = {}, acc1 = {}, acc2 = {};
    const int sw = (l16 & 7) << 4;
    const int ra = (wr * 16 + l16) << 10;
    const int rb = (wc * 16 + l16) << 10;
    #pragma unroll
    for (int s = 0; s < 16; ++s) {
        const int qo = ((s << 6) + (ks << 4)) ^ sw;
        bf16x8 ah = *(const bf16x8*)(lds + ra + qo);
        bf16x8 al = *(const bf16x8*)(lds + 32768 + ra + qo);
        bf16x8 bh = *(const bf16x8*)(lds + 65536 + rb + qo);
        bf16x8 bl = *(const bf16x8*)(lds + 98304 + rb + qo);
        acc0 = __builtin_amdgcn_mfma_f32_16x16x32_bf16(ah, bh, acc0, 0, 0, 0);
        acc1 = __builtin_amdgcn_mfma_f32_16x16x32_bf16(ah, bl, acc1, 0, 0, 0);
        acc2 = __builtin_amdgcn_mfma_f32_16x16x32_bf16(al, bh, acc2, 0, 0, 0);
    }

    const int orow = row0 + wr * 16 + (ks << 2);  // C/D: col=lane&15, row=(lane>>4)*4+j
    const int ocol = col0 + wc * 16 + l16;
    float cv[4];
    #pragma unroll
    for (int j = 0; j < 4; ++j) cv[j] = acc0[j] + acc1[j] + acc2[j];
    if (OUTMODE == 2) {
        u16x4 t4;
        #pragma unroll
        for (int j = 0; j < 4; ++j) t4[j] = f2bf(cv[j]);
        *(u16x4*)&CTh[ocol * 512 + orow] = t4;
    } else {
        u16x4 th4, tl4;
        #pragma unroll
        for (int j = 0; j < 4; ++j) {
            unsigned short hh, ll; split2(cv[j], hh, ll);
            th4[j] = hh; tl4[j] = ll;
            if (OUTMODE == 0) {
                Ch[(orow + j) * 512 + ocol] = hh;
                Cl[(orow + j) * 512 + ocol] = ll;
            }
        }
        *(u16x4*)&CTh[ocol * 512 + orow] = th4;
        *(u16x4*)&CTl[ocol * 512 + orow] = tl4;
    }
}

// squaring dispatch: 256 blocks, one 32x32 tile each
__global__ __launch_bounds__(256) void mm_sq(
        const unsigned short* __restrict__ Agh, const unsigned short* __restrict__ Agl,
        const unsigned short* __restrict__ BTh, const unsigned short* __restrict__ BTl,
        unsigned short* __restrict__ Ch, unsigned short* __restrict__ Cl,
        unsigned short* __restrict__ CTh, unsigned short* __restrict__ CTl) {
    __shared__ __align__(128) char lds[131072];
    const int bid = blockIdx.x;
    mm_tile<0>(Agh, Agl, BTh, BTl, Ch, Cl, CTh, CTl,
               (bid >> 4) << 5, (bid & 15) << 5, lds);
}

// merged dispatch: blocks 0..255 compute M^2; blocks 256..383 compute Q^T
__global__ __launch_bounds__(256) void mm_sq_q(
        const unsigned short* __restrict__ SMh, const unsigned short* __restrict__ SMl,
        const unsigned short* __restrict__ SMTh, const unsigned short* __restrict__ SMTl,
        const unsigned short* __restrict__ WOh, const unsigned short* __restrict__ WOl,
        unsigned short* __restrict__ Ch, unsigned short* __restrict__ Cl,
        unsigned short* __restrict__ CTh, unsigned short* __restrict__ CTl,
        unsigned short* __restrict__ QTh, unsigned short* __restrict__ QTl) {
    __shared__ __align__(128) char lds[131072];
    const int bid = blockIdx.x;
    if (bid < 256) {
        mm_tile<0>(SMh, SMl, SMTh, SMTl, Ch, Cl, CTh, CTl,
                   (bid >> 4) << 5, (bid & 15) << 5, lds);
    } else {
        const int q = bid - 256;   // 128 blocks over 512x256
        mm_tile<1>(SMh, SMl, WOh, WOl, nullptr, nullptr, QTh, QTl,
                   (q >> 3) << 5, (q & 7) << 5, lds);
    }
}

// P-fold dispatch: 128 blocks over 512x256, single-bf16 transposed output
__global__ __launch_bounds__(256) void mm_p(
        const unsigned short* __restrict__ Agh, const unsigned short* __restrict__ Agl,
        const unsigned short* __restrict__ QTh, const unsigned short* __restrict__ QTl,
        unsigned short* __restrict__ Ptb) {
    __shared__ __align__(128) char lds[131072];
    const int bid = blockIdx.x;
    mm_tile<2>(Agh, Agl, QTh, QTl, nullptr, nullptr, Ptb, nullptr,
               (bid >> 3) << 5, (bid & 7) << 5, lds);
}

// ---- out[16384 x 256] = X @ P.  Pt bf16 [256][512] = P^T (L2-resident). ----
// EXACT round-5-proven version: BM=32, BN=256 (4 waves x 64 cols), BK=64,
// grid 512 (2 blocks/CU). X staged fp32 via gld_lds (pre-swizzled source);
// B-frags direct from L2, lookahead-1; vmcnt(10)-counted, raw barriers.
__global__ __launch_bounds__(256, 2) void gemm_final(const float* __restrict__ X,
        const unsigned short* __restrict__ Pt, float* __restrict__ out) {
    __shared__ float XS[2][32][64];               // 8 KB per buffer, swizzled layout
    const int tid = threadIdx.x, lane = tid & 63, w = tid >> 6;
    const int l16 = lane & 15, ks = lane >> 4;
    const int row0 = blockIdx.x << 5;

    const int srow = tid >> 4;
    const int scs  = (((tid & 15) << 4) ^ ((srow & 7) << 4)) >> 2;   // float offset
    const float* xp0 = X + (row0 + srow) * 512 + scs;
    const float* xp1 = X + (row0 + 16 + srow) * 512 + scs;
    const unsigned short* bp = Pt + (w * 64 + l16) * 512 + ks * 8;

    f32x4 acc[2][4] = {};
    bf16x8 Breg[2][8];

    #define FG_STAGE(buf, t) {                                       \
        const int k_ = (t) << 6;                                     \
        gld_lds16(xp0 + k_, (char*)XS[buf] + tid * 16);              \
        gld_lds16(xp1 + k_, (char*)XS[buf] + 4096 + tid * 16);       \
    }
    #define FG_LOADB(set, t) {                                       \
        const int k_ = (t) << 6;                                     \
        _Pragma("unroll")                                            \
        for (int n = 0; n < 4; ++n)                                  \
            _Pragma("unroll")                                        \
            for (int s = 0; s < 2; ++s)                              \
                Breg[set][n * 2 + s] =                               \
                    *(const bf16x8*)&bp[n * 8192 + k_ + s * 32];     \
    }

    FG_STAGE(0, 0);
    FG_LOADB(0, 0);
    #pragma unroll
    for (int t = 0; t < 8; ++t) {
        const int buf = t & 1;
        if (t < 7) { FG_STAGE(buf ^ 1, t + 1); FG_LOADB(buf ^ 1, t + 1); }
        if (t < 7) asm volatile("s_waitcnt vmcnt(10)" ::: "memory");
        else       asm volatile("s_waitcnt vmcnt(0)" ::: "memory");
        __builtin_amdgcn_sched_barrier(0);
        __builtin_amdgcn_s_barrier();

        const int sw = (l16 & 7) << 4;
        #pragma unroll
        for (int m = 0; m < 2; ++m) {
            bf16x8 af[2];
            #pragma unroll
            for (int s = 0; s < 2; ++s) {
                const int q = (m * 16 + l16) * 256 + s * 128 + ks * 32;
                f32x4 v0 = *(const f32x4*)((const char*)XS[buf] + (q ^ sw));
                f32x4 v1 = *(const f32x4*)((const char*)XS[buf] + ((q + 16) ^ sw));
                #pragma unroll
                for (int j = 0; j < 4; ++j) {
                    af[s][j]     = (short)f2bf(v0[j]);
                    af[s][4 + j] = (short)f2bf(v1[j]);
                }
            }
            #pragma unroll
            for (int n = 0; n < 4; ++n) {
                acc[m][n] = __builtin_amdgcn_mfma_f32_16x16x32_bf16(af[0], Breg[buf][n * 2 + 0], acc[m][n], 0, 0, 0);
                acc[m][n] = __builtin_amdgcn_mfma_f32_16x16x32_bf16(af[1], Breg[buf][n * 2 + 1], acc[m][n], 0, 0, 0);
            }
        }
        __builtin_amdgcn_s_barrier();
    }
    #undef FG_STAGE
    #undef FG_LOADB

    #pragma unroll
    for (int m = 0; m < 2; ++m)
        #pragma unroll
        for (int n = 0; n < 4; ++n)
            #pragma unroll
            for (int j = 0; j < 4; ++j)
                out[(row0 + m * 16 + ks * 4 + j) * 256 + w * 64 + n * 16 + l16] = acc[m][n][j];
}

extern "C" void kernel_launch(void* const* d_in, const int* in_sizes, int n_in,
                              void* d_out, int out_size, void* d_ws, size_t ws_size,
                              hipStream_t stream) {
    const float* x     = (const float*)d_in[0];   // 16384 x 512
    const float* W     = (const float*)d_in[1];   // 512 x 512
    const float* w_out = (const float*)d_in[2];   // 256 x 512
    float* out = (float*)d_out;                   // 16384 x 256
    unsigned short* u = (unsigned short*)d_ws;

    const size_t SZ = 512 * 512, HZ = 256 * 512;
    unsigned short *SMh = u,           *SMl = u + SZ,     *SMTh = u + 2 * SZ,  *SMTl = u + 3 * SZ;
    unsigned short *S0h = u + 4 * SZ,  *S0l = u + 5 * SZ, *S0Th = u + 6 * SZ,  *S0Tl = u + 7 * SZ;
    unsigned short *S1h = u + 8 * SZ,  *S1l = u + 9 * SZ, *S1Th = u + 10 * SZ, *S1Tl = u + 11 * SZ;
    unsigned short *WOh = u + 12 * SZ, *WOl = WOh + HZ;
    unsigned short *QTh = u + 13 * SZ, *QTl = QTh + HZ;
    unsigned short *Ptb = u + 14 * SZ;

    dim3 blk(256);
    build_M<<<256, blk, 0, stream>>>(W, w_out, SMh, SMl, SMTh, SMTl, WOh, WOl);
    // D1: M^2 (256 blocks) + Q = M @ w_out^T (128 blocks) -- independent
    mm_sq_q<<<384, blk, 0, stream>>>(SMh, SMl, SMTh, SMTl, WOh, WOl,
                                     S0h, S0l, S0Th, S0Tl, QTh, QTl);
    mm_sq<<<256, blk, 0, stream>>>(S0h, S0l, S0Th, S0Tl, S1h, S1l, S1Th, S1Tl); // M^4
    mm_sq<<<256, blk, 0, stream>>>(S1h, S1l, S1Th, S1Tl, S0h, S0l, S0Th, S0Tl); // M^8
    mm_sq<<<256, blk, 0, stream>>>(S0h, S0l, S0Th, S0Tl, S1h, S1l, S1Th, S1Tl); // M^16
    mm_sq<<<256, blk, 0, stream>>>(S1h, S1l, S1Th, S1Tl, S0h, S0l, S0Th, S0Tl); // M^32
    mm_sq<<<256, blk, 0, stream>>>(S0h, S0l, S0Th, S0Tl, S1h, S1l, S1Th, S1Tl); // M^64 -> S1
    mm_p<<<128, blk, 0, stream>>>(S1h, S1l, QTh, QTl, Ptb);                      // Pt
    gemm_final<<<512, blk, 0, stream>>>(x, Ptb, out);
}